// Round 1
// baseline (1133.151 us; speedup 1.0000x reference)
//
#include <hip/hip_runtime.h>
#include <cstdint>

typedef unsigned long long ull;

#define NPTS 8192
#define NB 2
#define KNN 16
#define DM 128
#define NQ (NB * NPTS)          /* 16384 */
#define ROWS_TOTAL (NQ * KNN)   /* 262144 */

__device__ __forceinline__ float sq3f(float x, float y, float z) {
    return __fadd_rn(__fadd_rn(__fmul_rn(x, x), __fmul_rn(y, y)), __fmul_rn(z, z));
}
__device__ __forceinline__ float dot3f(float ax, float ay, float az, float bx, float by, float bz) {
    return __fadd_rn(__fadd_rn(__fmul_rn(ax, bx), __fmul_rn(ay, by)), __fmul_rn(az, bz));
}
__device__ __forceinline__ unsigned ford(float f) {
    unsigned u = __float_as_uint(f);
    return (u & 0x80000000u) ? ~u : (u | 0x80000000u);
}

// ---------------------------------------------------------------- KNN
// 1 query per wave, 4 waves/block. Top-16 by packed (distbits<<32)|idx key,
// exact tie semantics of jax.lax.top_k (lower index wins).
__global__ __launch_bounds__(256, 1) void knn_kernel(const float* __restrict__ xyz,
                                                     int* __restrict__ idx_out) {
    __shared__ float xs[1024 * 3];
    __shared__ ull lists[4][64][16];
    const int t = threadIdx.x;
    const int wv = t >> 6, lane = t & 63;
    const int q_id = blockIdx.x * 4 + wv;
    const int b = q_id >> 13;
    const int i = q_id & (NPTS - 1);
    const float* xb = xyz + (size_t)b * NPTS * 3;
    const float qx = xb[3 * i + 0], qy = xb[3 * i + 1], qz = xb[3 * i + 2];
    const float sqi = sq3f(qx, qy, qz);

    ull top[16];
#pragma unroll
    for (int m = 0; m < 16; m++) top[m] = ~0ull;

    for (int ch = 0; ch < 8; ++ch) {
        __syncthreads();
#pragma unroll
        for (int e = 0; e < 12; e++) {
            int id = t + e * 256;
            xs[id] = xb[ch * 3072 + id];
        }
        __syncthreads();
#pragma unroll
        for (int m = 0; m < 16; m++) {
            int jl = m * 64 + lane;
            int j = ch * 1024 + jl;
            float px = xs[3 * jl + 0], py = xs[3 * jl + 1], pz = xs[3 * jl + 2];
            float d = __fsub_rn(__fadd_rn(sqi, sq3f(px, py, pz)),
                                __fmul_rn(2.0f, dot3f(qx, qy, qz, px, py, pz)));
            ull key = ((ull)ford(d) << 32) | (unsigned)j;
            if (key < top[15]) {
                top[15] = key;
#pragma unroll
                for (int s = 15; s > 0; --s) {
                    if (top[s] < top[s - 1]) { ull tmp = top[s - 1]; top[s - 1] = top[s]; top[s] = tmp; }
                }
            }
        }
    }
#pragma unroll
    for (int m = 0; m < 16; m++) lists[wv][lane][m] = top[m];
    __syncthreads();
    for (int s = 1; s < 64; s <<= 1) {
        if ((lane & (2 * s - 1)) == 0) {
            const ull* A = lists[wv][lane];
            const ull* Bp = lists[wv][lane + s];
            ull out[16];
            int ia = 0, ib = 0;
#pragma unroll
            for (int m = 0; m < 16; m++) {
                ull va = (ia < 16) ? A[ia] : ~0ull;
                ull vb = (ib < 16) ? Bp[ib] : ~0ull;
                bool ta = (va <= vb);
                out[m] = ta ? va : vb;
                ia += ta ? 1 : 0;
                ib += ta ? 0 : 1;
            }
#pragma unroll
            for (int m = 0; m < 16; m++) lists[wv][lane][m] = out[m];
        }
        __syncthreads();
    }
    if (lane == 0) {
#pragma unroll
        for (int m = 0; m < 16; m++)
            idx_out[q_id * 16 + m] = (int)(unsigned)(lists[wv][0][m] & 0xffffffffu);
    }
}

// ---------------------------------------------------------------- x = features@fc1 + b
__global__ __launch_bounds__(256, 1) void gemm_x_kernel(const float* __restrict__ feats,
                                                        const float* __restrict__ w,
                                                        const float* __restrict__ bias,
                                                        float* __restrict__ xout) {
    __shared__ float At[64 * 65];
    __shared__ __align__(16) float Wt[64 * 128];
    const int t = threadIdx.x;
    const int base = blockIdx.x * 64;
#pragma unroll
    for (int e = 0; e < 16; e++) {
        int id = t + e * 256;
        int r = id >> 6, c = id & 63;
        At[c * 65 + r] = feats[(size_t)(base + r) * 64 + c];
    }
#pragma unroll
    for (int e = 0; e < 32; e++) { int id = t + e * 256; Wt[id] = w[id]; }
    __syncthreads();
    const int r0 = (t >> 4) * 4;
    const int c0 = (t & 15) * 8;
    float acc[4][8];
#pragma unroll
    for (int i = 0; i < 4; i++)
#pragma unroll
        for (int j = 0; j < 8; j++) acc[i][j] = bias[c0 + j];
#pragma unroll 4
    for (int kk = 0; kk < 64; ++kk) {
        float a0 = At[kk * 65 + r0 + 0];
        float a1 = At[kk * 65 + r0 + 1];
        float a2 = At[kk * 65 + r0 + 2];
        float a3 = At[kk * 65 + r0 + 3];
        const float4 w0 = *(const float4*)&Wt[kk * 128 + c0];
        const float4 w1 = *(const float4*)&Wt[kk * 128 + c0 + 4];
        float wj[8] = {w0.x, w0.y, w0.z, w0.w, w1.x, w1.y, w1.z, w1.w};
#pragma unroll
        for (int j = 0; j < 8; j++) {
            acc[0][j] += a0 * wj[j];
            acc[1][j] += a1 * wj[j];
            acc[2][j] += a2 * wj[j];
            acc[3][j] += a3 * wj[j];
        }
    }
#pragma unroll
    for (int i = 0; i < 4; i++)
#pragma unroll
        for (int j = 0; j < 8; j++)
            xout[(size_t)(base + r0 + i) * 128 + c0 + j] = acc[i][j];
}

// ---------------------------------------------------------------- q/xk/xv = x@W (no bias)
__global__ __launch_bounds__(256, 1) void gemm_qkv_kernel(const float* __restrict__ x,
                                                          const float* __restrict__ wq,
                                                          const float* __restrict__ wk,
                                                          const float* __restrict__ wv,
                                                          float* __restrict__ qo,
                                                          float* __restrict__ ko,
                                                          float* __restrict__ vo) {
    const float* w = (blockIdx.y == 0) ? wq : ((blockIdx.y == 1) ? wk : wv);
    float* o = (blockIdx.y == 0) ? qo : ((blockIdx.y == 1) ? ko : vo);
    __shared__ float At[128 * 65];
    __shared__ __align__(16) float Wt[128 * 128];
    const int t = threadIdx.x;
    const int base = blockIdx.x * 64;
#pragma unroll
    for (int e = 0; e < 32; e++) {
        int id = t + e * 256;
        int r = id >> 7, c = id & 127;
        At[c * 65 + r] = x[(size_t)(base + r) * 128 + c];
    }
#pragma unroll
    for (int e = 0; e < 64; e++) { int id = t + e * 256; Wt[id] = w[id]; }
    __syncthreads();
    const int r0 = (t >> 4) * 4;
    const int c0 = (t & 15) * 8;
    float acc[4][8];
#pragma unroll
    for (int i = 0; i < 4; i++)
#pragma unroll
        for (int j = 0; j < 8; j++) acc[i][j] = 0.0f;
#pragma unroll 4
    for (int kk = 0; kk < 128; ++kk) {
        float a0 = At[kk * 65 + r0 + 0];
        float a1 = At[kk * 65 + r0 + 1];
        float a2 = At[kk * 65 + r0 + 2];
        float a3 = At[kk * 65 + r0 + 3];
        const float4 w0 = *(const float4*)&Wt[kk * 128 + c0];
        const float4 w1 = *(const float4*)&Wt[kk * 128 + c0 + 4];
        float wj[8] = {w0.x, w0.y, w0.z, w0.w, w1.x, w1.y, w1.z, w1.w};
#pragma unroll
        for (int j = 0; j < 8; j++) {
            acc[0][j] += a0 * wj[j];
            acc[1][j] += a1 * wj[j];
            acc[2][j] += a2 * wj[j];
            acc[3][j] += a3 * wj[j];
        }
    }
#pragma unroll
    for (int i = 0; i < 4; i++)
#pragma unroll
        for (int j = 0; j < 8; j++)
            o[(size_t)(base + r0 + i) * 128 + c0 + j] = acc[i][j];
}

// ---------------------------------------------------------------- fused: pos_enc -> h -> u = relu(h@g1+b)
__global__ __launch_bounds__(256, 1) void k3_kernel(const float* __restrict__ xyz,
                                                    const int* __restrict__ idxw,
                                                    const float* __restrict__ q,
                                                    const float* __restrict__ xk,
                                                    const float* __restrict__ d1,
                                                    const float* __restrict__ bd1,
                                                    const float* __restrict__ d2,
                                                    const float* __restrict__ bd2,
                                                    const float* __restrict__ g1,
                                                    const float* __restrict__ bg1,
                                                    float* __restrict__ uout) {
    __shared__ float Ab[128 * 129];
    __shared__ __align__(16) float Wb[128 * 128];
    __shared__ float d1s[3 * 128];
    __shared__ float bd1s[128], bd2s[128], bg1s[128];
    __shared__ float rels[128 * 3];
    __shared__ int jrow[128];

    const int t = threadIdx.x;
    const int R0 = blockIdx.x * 128;
    const int b = R0 >> 17;
    const int nkbase = R0 & 131071;

#pragma unroll
    for (int e = 0; e < 2; e++) { int id = t + e * 256; if (id < 384) d1s[id] = d1[id]; }
    if (t < 128) { bd1s[t] = bd1[t]; bd2s[t] = bd2[t]; bg1s[t] = bg1[t]; }
    if (t < 128) {
        int nk = nkbase + t;
        int n = nk >> 4;
        int j = idxw[R0 + t];
        jrow[t] = j;
        const float* pn = xyz + ((size_t)b * NPTS + n) * 3;
        const float* pj = xyz + ((size_t)b * NPTS + j) * 3;
        rels[t * 3 + 0] = pn[0] - pj[0];
        rels[t * 3 + 1] = pn[1] - pj[1];
        rels[t * 3 + 2] = pn[2] - pj[2];
    }
#pragma unroll
    for (int e = 0; e < 64; e++) { int id = t + e * 256; Wb[id] = d2[id]; }
    __syncthreads();

    // T = relu(rel @ d1 + bd1), stored transposed Ab[c][r]
    {
        const int r = t & 127;
        const float rx = rels[r * 3 + 0], ry = rels[r * 3 + 1], rz = rels[r * 3 + 2];
#pragma unroll
        for (int e = 0; e < 64; e++) {
            int c = (t >> 7) + e * 2;
            float v = rx * d1s[c] + ry * d1s[128 + c] + rz * d1s[256 + c] + bd1s[c];
            Ab[c * 129 + r] = fmaxf(v, 0.0f);
        }
    }
    __syncthreads();

    const int r0 = (t >> 3) * 4;
    const int c0 = (t & 7) * 16;

    // pos = relu(T @ d2 + bd2)
    float pos[4][16];
#pragma unroll
    for (int i = 0; i < 4; i++)
#pragma unroll
        for (int j = 0; j < 16; j++) pos[i][j] = bd2s[c0 + j];
#pragma unroll 4
    for (int kk = 0; kk < 128; ++kk) {
        float a0 = Ab[kk * 129 + r0 + 0];
        float a1 = Ab[kk * 129 + r0 + 1];
        float a2 = Ab[kk * 129 + r0 + 2];
        float a3 = Ab[kk * 129 + r0 + 3];
        const float4 w0 = *(const float4*)&Wb[kk * 128 + c0];
        const float4 w1 = *(const float4*)&Wb[kk * 128 + c0 + 4];
        const float4 w2 = *(const float4*)&Wb[kk * 128 + c0 + 8];
        const float4 w3 = *(const float4*)&Wb[kk * 128 + c0 + 12];
        float wj[16] = {w0.x, w0.y, w0.z, w0.w, w1.x, w1.y, w1.z, w1.w,
                        w2.x, w2.y, w2.z, w2.w, w3.x, w3.y, w3.z, w3.w};
#pragma unroll
        for (int j = 0; j < 16; j++) {
            pos[0][j] += a0 * wj[j];
            pos[1][j] += a1 * wj[j];
            pos[2][j] += a2 * wj[j];
            pos[3][j] += a3 * wj[j];
        }
    }
#pragma unroll
    for (int i = 0; i < 4; i++)
#pragma unroll
        for (int j = 0; j < 16; j++) pos[i][j] = fmaxf(pos[i][j], 0.0f);
    __syncthreads();

    // load g1; h = q - k_nbr + pos -> Ab[c][r]
#pragma unroll
    for (int e = 0; e < 64; e++) { int id = t + e * 256; Wb[id] = g1[id]; }
    {
        int n = (nkbase + r0) >> 4;
        const float* qrow = q + ((size_t)b * NPTS + n) * 128 + c0;
#pragma unroll
        for (int i = 0; i < 4; i++) {
            int j = jrow[r0 + i];
            const float* krow = xk + ((size_t)b * NPTS + j) * 128 + c0;
#pragma unroll
            for (int jj = 0; jj < 16; jj++) {
                float h = pos[i][jj] + qrow[jj] - krow[jj];
                Ab[(c0 + jj) * 129 + (r0 + i)] = h;
            }
        }
    }
    __syncthreads();

    // u = relu(h @ g1 + bg1)
    float acc[4][16];
#pragma unroll
    for (int i = 0; i < 4; i++)
#pragma unroll
        for (int j = 0; j < 16; j++) acc[i][j] = bg1s[c0 + j];
#pragma unroll 4
    for (int kk = 0; kk < 128; ++kk) {
        float a0 = Ab[kk * 129 + r0 + 0];
        float a1 = Ab[kk * 129 + r0 + 1];
        float a2 = Ab[kk * 129 + r0 + 2];
        float a3 = Ab[kk * 129 + r0 + 3];
        const float4 w0 = *(const float4*)&Wb[kk * 128 + c0];
        const float4 w1 = *(const float4*)&Wb[kk * 128 + c0 + 4];
        const float4 w2 = *(const float4*)&Wb[kk * 128 + c0 + 8];
        const float4 w3 = *(const float4*)&Wb[kk * 128 + c0 + 12];
        float wj[16] = {w0.x, w0.y, w0.z, w0.w, w1.x, w1.y, w1.z, w1.w,
                        w2.x, w2.y, w2.z, w2.w, w3.x, w3.y, w3.z, w3.w};
#pragma unroll
        for (int j = 0; j < 16; j++) {
            acc[0][j] += a0 * wj[j];
            acc[1][j] += a1 * wj[j];
            acc[2][j] += a2 * wj[j];
            acc[3][j] += a3 * wj[j];
        }
    }
#pragma unroll
    for (int i = 0; i < 4; i++)
#pragma unroll
        for (int j = 0; j < 16; j++)
            uout[(size_t)(R0 + r0 + i) * 128 + c0 + j] = fmaxf(acc[i][j], 0.0f);
}

// ---------------------------------------------------------------- logits = u@g2+b, softmax over k, in-place in attn region
__global__ __launch_bounds__(256, 1) void k4_kernel(const float* __restrict__ g2,
                                                    const float* __restrict__ bg2,
                                                    float* __restrict__ attn) {
    __shared__ float Ab[128 * 129];
    __shared__ __align__(16) float Wb[128 * 128];
    __shared__ float bg2s[128];
    const int t = threadIdx.x;
    const int R0 = blockIdx.x * 128;
#pragma unroll
    for (int e = 0; e < 64; e++) {
        int id = t + e * 256;
        int r = id >> 7, c = id & 127;
        Ab[c * 129 + r] = attn[(size_t)(R0 + r) * 128 + c];
    }
#pragma unroll
    for (int e = 0; e < 64; e++) { int id = t + e * 256; Wb[id] = g2[id]; }
    if (t < 128) bg2s[t] = bg2[t];
    __syncthreads();

    const int r0 = (t >> 3) * 4;
    const int c0 = (t & 7) * 16;
    float acc[4][16];
#pragma unroll
    for (int i = 0; i < 4; i++)
#pragma unroll
        for (int j = 0; j < 16; j++) acc[i][j] = bg2s[c0 + j];
#pragma unroll 4
    for (int kk = 0; kk < 128; ++kk) {
        float a0 = Ab[kk * 129 + r0 + 0];
        float a1 = Ab[kk * 129 + r0 + 1];
        float a2 = Ab[kk * 129 + r0 + 2];
        float a3 = Ab[kk * 129 + r0 + 3];
        const float4 w0 = *(const float4*)&Wb[kk * 128 + c0];
        const float4 w1 = *(const float4*)&Wb[kk * 128 + c0 + 4];
        const float4 w2 = *(const float4*)&Wb[kk * 128 + c0 + 8];
        const float4 w3 = *(const float4*)&Wb[kk * 128 + c0 + 12];
        float wj[16] = {w0.x, w0.y, w0.z, w0.w, w1.x, w1.y, w1.z, w1.w,
                        w2.x, w2.y, w2.z, w2.w, w3.x, w3.y, w3.z, w3.w};
#pragma unroll
        for (int j = 0; j < 16; j++) {
            acc[0][j] += a0 * wj[j];
            acc[1][j] += a1 * wj[j];
            acc[2][j] += a2 * wj[j];
            acc[3][j] += a3 * wj[j];
        }
    }
    const float scale = 0.08838834764831845f; /* 1/sqrt(128) */
    __syncthreads();
#pragma unroll
    for (int i = 0; i < 4; i++)
#pragma unroll
        for (int j = 0; j < 16; j++)
            Ab[(c0 + j) * 129 + (r0 + i)] = acc[i][j] * scale;
    __syncthreads();

    // softmax over the 16 neighbors for each (n_local, channel)
#pragma unroll
    for (int e = 0; e < 4; e++) {
        int p = t + e * 256;
        int n = p >> 7, c = p & 127;
        float* col = &Ab[c * 129 + n * 16];
        float mx = col[0];
#pragma unroll
        for (int k = 1; k < 16; k++) mx = fmaxf(mx, col[k]);
        float ex[16];
        float s = 0.0f;
#pragma unroll
        for (int k = 0; k < 16; k++) { ex[k] = expf(col[k] - mx); s += ex[k]; }
        float inv = 1.0f / s;
#pragma unroll
        for (int k = 0; k < 16; k++) col[k] = ex[k] * inv;
    }
    __syncthreads();
#pragma unroll
    for (int e = 0; e < 64; e++) {
        int id = t + e * 256;
        int r = id >> 7, c = id & 127;
        attn[(size_t)(R0 + r) * 128 + c] = Ab[c * 129 + r];
    }
}

// ---------------------------------------------------------------- res_pre = sum_k attn*(v_nbr + pos)  (pos recomputed)
__global__ __launch_bounds__(256, 1) void k5_kernel(const float* __restrict__ xyz,
                                                    const int* __restrict__ idxw,
                                                    const float* __restrict__ xv,
                                                    const float* __restrict__ d1,
                                                    const float* __restrict__ bd1,
                                                    const float* __restrict__ d2,
                                                    const float* __restrict__ bd2,
                                                    const float* __restrict__ attn,
                                                    float* __restrict__ res_pre) {
    __shared__ float Ab[128 * 129];
    __shared__ __align__(16) float Wb[128 * 128];
    __shared__ float d1s[3 * 128];
    __shared__ float bd1s[128], bd2s[128];
    __shared__ float rels[128 * 3];
    __shared__ int jrow[128];
    __shared__ float part[4][8][128];

    const int t = threadIdx.x;
    const int R0 = blockIdx.x * 128;
    const int b = R0 >> 17;
    const int nkbase = R0 & 131071;

#pragma unroll
    for (int e = 0; e < 2; e++) { int id = t + e * 256; if (id < 384) d1s[id] = d1[id]; }
    if (t < 128) { bd1s[t] = bd1[t]; bd2s[t] = bd2[t]; }
    if (t < 128) {
        int nk = nkbase + t;
        int n = nk >> 4;
        int j = idxw[R0 + t];
        jrow[t] = j;
        const float* pn = xyz + ((size_t)b * NPTS + n) * 3;
        const float* pj = xyz + ((size_t)b * NPTS + j) * 3;
        rels[t * 3 + 0] = pn[0] - pj[0];
        rels[t * 3 + 1] = pn[1] - pj[1];
        rels[t * 3 + 2] = pn[2] - pj[2];
    }
#pragma unroll
    for (int e = 0; e < 64; e++) { int id = t + e * 256; Wb[id] = d2[id]; }
    __syncthreads();

    {
        const int r = t & 127;
        const float rx = rels[r * 3 + 0], ry = rels[r * 3 + 1], rz = rels[r * 3 + 2];
#pragma unroll
        for (int e = 0; e < 64; e++) {
            int c = (t >> 7) + e * 2;
            float v = rx * d1s[c] + ry * d1s[128 + c] + rz * d1s[256 + c] + bd1s[c];
            Ab[c * 129 + r] = fmaxf(v, 0.0f);
        }
    }
    __syncthreads();

    const int r0 = (t >> 3) * 4;
    const int c0 = (t & 7) * 16;
    float pos[4][16];
#pragma unroll
    for (int i = 0; i < 4; i++)
#pragma unroll
        for (int j = 0; j < 16; j++) pos[i][j] = bd2s[c0 + j];
#pragma unroll 4
    for (int kk = 0; kk < 128; ++kk) {
        float a0 = Ab[kk * 129 + r0 + 0];
        float a1 = Ab[kk * 129 + r0 + 1];
        float a2 = Ab[kk * 129 + r0 + 2];
        float a3 = Ab[kk * 129 + r0 + 3];
        const float4 w0 = *(const float4*)&Wb[kk * 128 + c0];
        const float4 w1 = *(const float4*)&Wb[kk * 128 + c0 + 4];
        const float4 w2 = *(const float4*)&Wb[kk * 128 + c0 + 8];
        const float4 w3 = *(const float4*)&Wb[kk * 128 + c0 + 12];
        float wj[16] = {w0.x, w0.y, w0.z, w0.w, w1.x, w1.y, w1.z, w1.w,
                        w2.x, w2.y, w2.z, w2.w, w3.x, w3.y, w3.z, w3.w};
#pragma unroll
        for (int j = 0; j < 16; j++) {
            pos[0][j] += a0 * wj[j];
            pos[1][j] += a1 * wj[j];
            pos[2][j] += a2 * wj[j];
            pos[3][j] += a3 * wj[j];
        }
    }
#pragma unroll
    for (int i = 0; i < 4; i++)
#pragma unroll
        for (int j = 0; j < 16; j++) pos[i][j] = fmaxf(pos[i][j], 0.0f);

    float partial[16];
#pragma unroll
    for (int j = 0; j < 16; j++) partial[j] = 0.0f;
#pragma unroll
    for (int i = 0; i < 4; i++) {
        const float* arow = attn + (size_t)(R0 + r0 + i) * 128 + c0;
        int j = jrow[r0 + i];
        const float* vrow = xv + ((size_t)b * NPTS + j) * 128 + c0;
#pragma unroll
        for (int jj = 0; jj < 16; jj++)
            partial[jj] += arow[jj] * (vrow[jj] + pos[i][jj]);
    }
    const int slot = (r0 >> 2) & 3;
    const int nl = r0 >> 4;
#pragma unroll
    for (int jj = 0; jj < 16; jj++) part[slot][nl][c0 + jj] = partial[jj];
    __syncthreads();
#pragma unroll
    for (int e = 0; e < 4; e++) {
        int p = t + e * 256;
        int n = p >> 7, c = p & 127;
        float s = ((part[0][n][c] + part[1][n][c]) + part[2][n][c]) + part[3][n][c];
        res_pre[(size_t)((R0 >> 4) + n) * 128 + c] = s;
    }
}

// ---------------------------------------------------------------- res = res_pre@fc2 + b + features
__global__ __launch_bounds__(256, 1) void k6_kernel(const float* __restrict__ res_pre,
                                                    const float* __restrict__ w,
                                                    const float* __restrict__ bias,
                                                    const float* __restrict__ feats,
                                                    float* __restrict__ res_out) {
    __shared__ float At[128 * 65];
    __shared__ __align__(16) float Wt[128 * 64];
    const int t = threadIdx.x;
    const int base = blockIdx.x * 64;
#pragma unroll
    for (int e = 0; e < 32; e++) {
        int id = t + e * 256;
        int r = id >> 7, c = id & 127;
        At[c * 65 + r] = res_pre[(size_t)(base + r) * 128 + c];
    }
#pragma unroll
    for (int e = 0; e < 32; e++) { int id = t + e * 256; Wt[id] = w[id]; }
    __syncthreads();
    const int r0 = (t >> 4) * 4;
    const int c0 = (t & 15) * 4;
    float acc[4][4];
#pragma unroll
    for (int i = 0; i < 4; i++)
#pragma unroll
        for (int j = 0; j < 4; j++) acc[i][j] = bias[c0 + j];
#pragma unroll 4
    for (int kk = 0; kk < 128; ++kk) {
        float a0 = At[kk * 65 + r0 + 0];
        float a1 = At[kk * 65 + r0 + 1];
        float a2 = At[kk * 65 + r0 + 2];
        float a3 = At[kk * 65 + r0 + 3];
        const float4 w0 = *(const float4*)&Wt[kk * 64 + c0];
        float wj[4] = {w0.x, w0.y, w0.z, w0.w};
#pragma unroll
        for (int j = 0; j < 4; j++) {
            acc[0][j] += a0 * wj[j];
            acc[1][j] += a1 * wj[j];
            acc[2][j] += a2 * wj[j];
            acc[3][j] += a3 * wj[j];
        }
    }
#pragma unroll
    for (int i = 0; i < 4; i++)
#pragma unroll
        for (int j = 0; j < 4; j++)
            res_out[(size_t)(base + r0 + i) * 64 + c0 + j] =
                acc[i][j] + feats[(size_t)(base + r0 + i) * 64 + c0 + j];
}

extern "C" void kernel_launch(void* const* d_in, const int* in_sizes, int n_in,
                              void* d_out, int out_size, void* d_ws, size_t ws_size,
                              hipStream_t stream) {
    (void)in_sizes; (void)n_in; (void)out_size; (void)ws_size;
    const float* xyz   = (const float*)d_in[0];
    const float* feats = (const float*)d_in[2];
    const float* fc1_w = (const float*)d_in[3];
    const float* fc1_b = (const float*)d_in[4];
    const float* fc2_w = (const float*)d_in[5];
    const float* fc2_b = (const float*)d_in[6];
    const float* g1    = (const float*)d_in[7];
    const float* bg1   = (const float*)d_in[8];
    const float* g2    = (const float*)d_in[9];
    const float* bg2   = (const float*)d_in[10];
    const float* d1    = (const float*)d_in[11];
    const float* bd1   = (const float*)d_in[12];
    const float* d2    = (const float*)d_in[13];
    const float* bd2   = (const float*)d_in[14];
    const float* wq    = (const float*)d_in[15];
    const float* wk    = (const float*)d_in[16];
    const float* wv    = (const float*)d_in[17];

    int* idxw   = (int*)d_ws;
    float* xbuf = (float*)((char*)d_ws + (1 << 20));
    float* qbuf = xbuf + 2097152;
    float* kbuf = qbuf + 2097152;
    float* vbuf = kbuf + 2097152;
    float* rpre = vbuf + 2097152;

    float* res_out = (float*)d_out;
    float* attn    = res_out + 1048576;  /* u lives here between k3 and k4 */

    knn_kernel<<<4096, 256, 0, stream>>>(xyz, idxw);
    gemm_x_kernel<<<256, 256, 0, stream>>>(feats, fc1_w, fc1_b, xbuf);
    gemm_qkv_kernel<<<dim3(256, 3), 256, 0, stream>>>(xbuf, wq, wk, wv, qbuf, kbuf, vbuf);
    k3_kernel<<<2048, 256, 0, stream>>>(xyz, idxw, qbuf, kbuf, d1, bd1, d2, bd2, g1, bg1, attn);
    k4_kernel<<<2048, 256, 0, stream>>>(g2, bg2, attn);
    k5_kernel<<<2048, 256, 0, stream>>>(xyz, idxw, vbuf, d1, bd1, d2, bd2, attn, rpre);
    k6_kernel<<<256, 256, 0, stream>>>(rpre, fc2_w, fc2_b, feats, res_out);
}

// Round 2
// 919.005 us; speedup vs baseline: 1.2330x; 1.2330x over previous
//
#include <hip/hip_runtime.h>
#include <cstdint>

typedef unsigned long long ull;

#define NPTS 8192
#define NB 2
#define KNN 16
#define DM 128
#define NQ (NB * NPTS)          /* 16384 */
#define ROWS_TOTAL (NQ * KNN)   /* 262144 */

__device__ __forceinline__ float sq3f(float x, float y, float z) {
    return __fadd_rn(__fadd_rn(__fmul_rn(x, x), __fmul_rn(y, y)), __fmul_rn(z, z));
}
__device__ __forceinline__ float dot3f(float ax, float ay, float az, float bx, float by, float bz) {
    return __fadd_rn(__fadd_rn(__fmul_rn(ax, bx), __fmul_rn(ay, by)), __fmul_rn(az, bz));
}
__device__ __forceinline__ unsigned ford(float f) {
    unsigned u = __float_as_uint(f);
    return (u & 0x80000000u) ? ~u : (u | 0x80000000u);
}

// ---------------------------------------------------------------- KNN
// Wave-cooperative top-16: one query per wave; sorted top-16 lives in lanes
// 0..15 (ascending, lane15 = current 16th-smallest = threshold). Per batch of
// 64 candidates: uniform ballot check vs threshold; only triggered batches
// (~49/128 in expectation) run the shfl-up parallel insert. Keys are packed
// (ordered_dist_bits<<32)|idx -> exact jax.lax.top_k tie semantics.
__global__ __launch_bounds__(256) void knn_kernel(const float* __restrict__ xyz,
                                                  int* __restrict__ idx_out) {
    __shared__ float xs[1024 * 3];
    __shared__ float sj[1024];
    const int t = threadIdx.x;
    const int wv = t >> 6, lane = t & 63;
    const int q_id = blockIdx.x * 4 + wv;
    const int b = q_id >> 13;
    const int i = q_id & (NPTS - 1);
    const float* xb = xyz + (size_t)b * NPTS * 3;
    const float qx = xb[3 * i + 0], qy = xb[3 * i + 1], qz = xb[3 * i + 2];
    const float sqi = sq3f(qx, qy, qz);

    ull list = ~0ull;   // lanes 0..15: sorted top-16 keys (ascending); others: don't-care
    ull thr = ~0ull;    // wave-uniform copy of lane15's key

    for (int ch = 0; ch < 8; ++ch) {
        __syncthreads();
#pragma unroll
        for (int e = 0; e < 12; e++) {
            int id = t + e * 256;
            xs[id] = xb[ch * 3072 + id];
        }
        __syncthreads();
#pragma unroll
        for (int e = 0; e < 4; e++) {
            int jl = t + e * 256;
            sj[jl] = sq3f(xs[3 * jl + 0], xs[3 * jl + 1], xs[3 * jl + 2]);
        }
        __syncthreads();
#pragma unroll 2
        for (int m = 0; m < 16; m++) {
            int jl = m * 64 + lane;
            int j = ch * 1024 + jl;
            float px = xs[3 * jl + 0], py = xs[3 * jl + 1], pz = xs[3 * jl + 2];
            float d = __fsub_rn(__fadd_rn(sqi, sj[jl]),
                                __fmul_rn(2.0f, dot3f(qx, qy, qz, px, py, pz)));
            ull key = ((ull)ford(d) << 32) | (unsigned)j;
            ull ballot = __ballot(key < thr);
            if (ballot == 0ull) continue;   // wave-uniform branch
            do {
                int l = __builtin_ctzll(ballot);
                ballot &= ballot - 1;
                ull ck = __shfl(key, l);
                // parallel insert into sorted lanes 0..15 (stale ck -> no-op)
                ull prev = __shfl_up(list, 1);
                bool shift = (ck < list);
                list = shift ? ((lane == 0 || ck >= prev) ? ck : prev) : list;
            } while (ballot);
            thr = __shfl(list, 15);
        }
    }
    if (lane < 16)
        idx_out[q_id * 16 + lane] = (int)(unsigned)(list & 0xffffffffu);
}

// ---------------------------------------------------------------- x = features@fc1 + b
__global__ __launch_bounds__(256, 1) void gemm_x_kernel(const float* __restrict__ feats,
                                                        const float* __restrict__ w,
                                                        const float* __restrict__ bias,
                                                        float* __restrict__ xout) {
    __shared__ float At[64 * 65];
    __shared__ __align__(16) float Wt[64 * 128];
    const int t = threadIdx.x;
    const int base = blockIdx.x * 64;
#pragma unroll
    for (int e = 0; e < 16; e++) {
        int id = t + e * 256;
        int r = id >> 6, c = id & 63;
        At[c * 65 + r] = feats[(size_t)(base + r) * 64 + c];
    }
#pragma unroll
    for (int e = 0; e < 32; e++) { int id = t + e * 256; Wt[id] = w[id]; }
    __syncthreads();
    const int r0 = (t >> 4) * 4;
    const int c0 = (t & 15) * 8;
    float acc[4][8];
#pragma unroll
    for (int i = 0; i < 4; i++)
#pragma unroll
        for (int j = 0; j < 8; j++) acc[i][j] = bias[c0 + j];
#pragma unroll 4
    for (int kk = 0; kk < 64; ++kk) {
        float a0 = At[kk * 65 + r0 + 0];
        float a1 = At[kk * 65 + r0 + 1];
        float a2 = At[kk * 65 + r0 + 2];
        float a3 = At[kk * 65 + r0 + 3];
        const float4 w0 = *(const float4*)&Wt[kk * 128 + c0];
        const float4 w1 = *(const float4*)&Wt[kk * 128 + c0 + 4];
        float wj[8] = {w0.x, w0.y, w0.z, w0.w, w1.x, w1.y, w1.z, w1.w};
#pragma unroll
        for (int j = 0; j < 8; j++) {
            acc[0][j] += a0 * wj[j];
            acc[1][j] += a1 * wj[j];
            acc[2][j] += a2 * wj[j];
            acc[3][j] += a3 * wj[j];
        }
    }
#pragma unroll
    for (int i = 0; i < 4; i++)
#pragma unroll
        for (int j = 0; j < 8; j++)
            xout[(size_t)(base + r0 + i) * 128 + c0 + j] = acc[i][j];
}

// ---------------------------------------------------------------- q/xk/xv = x@W (no bias)
__global__ __launch_bounds__(256, 1) void gemm_qkv_kernel(const float* __restrict__ x,
                                                          const float* __restrict__ wq,
                                                          const float* __restrict__ wk,
                                                          const float* __restrict__ wv,
                                                          float* __restrict__ qo,
                                                          float* __restrict__ ko,
                                                          float* __restrict__ vo) {
    const float* w = (blockIdx.y == 0) ? wq : ((blockIdx.y == 1) ? wk : wv);
    float* o = (blockIdx.y == 0) ? qo : ((blockIdx.y == 1) ? ko : vo);
    __shared__ float At[128 * 65];
    __shared__ __align__(16) float Wt[128 * 128];
    const int t = threadIdx.x;
    const int base = blockIdx.x * 64;
#pragma unroll
    for (int e = 0; e < 32; e++) {
        int id = t + e * 256;
        int r = id >> 7, c = id & 127;
        At[c * 65 + r] = x[(size_t)(base + r) * 128 + c];
    }
#pragma unroll
    for (int e = 0; e < 64; e++) { int id = t + e * 256; Wt[id] = w[id]; }
    __syncthreads();
    const int r0 = (t >> 4) * 4;
    const int c0 = (t & 15) * 8;
    float acc[4][8];
#pragma unroll
    for (int i = 0; i < 4; i++)
#pragma unroll
        for (int j = 0; j < 8; j++) acc[i][j] = 0.0f;
#pragma unroll 4
    for (int kk = 0; kk < 128; ++kk) {
        float a0 = At[kk * 65 + r0 + 0];
        float a1 = At[kk * 65 + r0 + 1];
        float a2 = At[kk * 65 + r0 + 2];
        float a3 = At[kk * 65 + r0 + 3];
        const float4 w0 = *(const float4*)&Wt[kk * 128 + c0];
        const float4 w1 = *(const float4*)&Wt[kk * 128 + c0 + 4];
        float wj[8] = {w0.x, w0.y, w0.z, w0.w, w1.x, w1.y, w1.z, w1.w};
#pragma unroll
        for (int j = 0; j < 8; j++) {
            acc[0][j] += a0 * wj[j];
            acc[1][j] += a1 * wj[j];
            acc[2][j] += a2 * wj[j];
            acc[3][j] += a3 * wj[j];
        }
    }
#pragma unroll
    for (int i = 0; i < 4; i++)
#pragma unroll
        for (int j = 0; j < 8; j++)
            o[(size_t)(base + r0 + i) * 128 + c0 + j] = acc[i][j];
}

// ---------------------------------------------------------------- fused: pos_enc -> h -> u = relu(h@g1+b)
__global__ __launch_bounds__(256, 1) void k3_kernel(const float* __restrict__ xyz,
                                                    const int* __restrict__ idxw,
                                                    const float* __restrict__ q,
                                                    const float* __restrict__ xk,
                                                    const float* __restrict__ d1,
                                                    const float* __restrict__ bd1,
                                                    const float* __restrict__ d2,
                                                    const float* __restrict__ bd2,
                                                    const float* __restrict__ g1,
                                                    const float* __restrict__ bg1,
                                                    float* __restrict__ uout) {
    __shared__ float Ab[128 * 129];
    __shared__ __align__(16) float Wb[128 * 128];
    __shared__ float d1s[3 * 128];
    __shared__ float bd1s[128], bd2s[128], bg1s[128];
    __shared__ float rels[128 * 3];
    __shared__ int jrow[128];

    const int t = threadIdx.x;
    const int R0 = blockIdx.x * 128;
    const int b = R0 >> 17;
    const int nkbase = R0 & 131071;

#pragma unroll
    for (int e = 0; e < 2; e++) { int id = t + e * 256; if (id < 384) d1s[id] = d1[id]; }
    if (t < 128) { bd1s[t] = bd1[t]; bd2s[t] = bd2[t]; bg1s[t] = bg1[t]; }
    if (t < 128) {
        int nk = nkbase + t;
        int n = nk >> 4;
        int j = idxw[R0 + t];
        jrow[t] = j;
        const float* pn = xyz + ((size_t)b * NPTS + n) * 3;
        const float* pj = xyz + ((size_t)b * NPTS + j) * 3;
        rels[t * 3 + 0] = pn[0] - pj[0];
        rels[t * 3 + 1] = pn[1] - pj[1];
        rels[t * 3 + 2] = pn[2] - pj[2];
    }
#pragma unroll
    for (int e = 0; e < 64; e++) { int id = t + e * 256; Wb[id] = d2[id]; }
    __syncthreads();

    // T = relu(rel @ d1 + bd1), stored transposed Ab[c][r]
    {
        const int r = t & 127;
        const float rx = rels[r * 3 + 0], ry = rels[r * 3 + 1], rz = rels[r * 3 + 2];
#pragma unroll
        for (int e = 0; e < 64; e++) {
            int c = (t >> 7) + e * 2;
            float v = rx * d1s[c] + ry * d1s[128 + c] + rz * d1s[256 + c] + bd1s[c];
            Ab[c * 129 + r] = fmaxf(v, 0.0f);
        }
    }
    __syncthreads();

    const int r0 = (t >> 3) * 4;
    const int c0 = (t & 7) * 16;

    // pos = relu(T @ d2 + bd2)
    float pos[4][16];
#pragma unroll
    for (int i = 0; i < 4; i++)
#pragma unroll
        for (int j = 0; j < 16; j++) pos[i][j] = bd2s[c0 + j];
#pragma unroll 4
    for (int kk = 0; kk < 128; ++kk) {
        float a0 = Ab[kk * 129 + r0 + 0];
        float a1 = Ab[kk * 129 + r0 + 1];
        float a2 = Ab[kk * 129 + r0 + 2];
        float a3 = Ab[kk * 129 + r0 + 3];
        const float4 w0 = *(const float4*)&Wb[kk * 128 + c0];
        const float4 w1 = *(const float4*)&Wb[kk * 128 + c0 + 4];
        const float4 w2 = *(const float4*)&Wb[kk * 128 + c0 + 8];
        const float4 w3 = *(const float4*)&Wb[kk * 128 + c0 + 12];
        float wj[16] = {w0.x, w0.y, w0.z, w0.w, w1.x, w1.y, w1.z, w1.w,
                        w2.x, w2.y, w2.z, w2.w, w3.x, w3.y, w3.z, w3.w};
#pragma unroll
        for (int j = 0; j < 16; j++) {
            pos[0][j] += a0 * wj[j];
            pos[1][j] += a1 * wj[j];
            pos[2][j] += a2 * wj[j];
            pos[3][j] += a3 * wj[j];
        }
    }
#pragma unroll
    for (int i = 0; i < 4; i++)
#pragma unroll
        for (int j = 0; j < 16; j++) pos[i][j] = fmaxf(pos[i][j], 0.0f);
    __syncthreads();

    // load g1; h = q - k_nbr + pos -> Ab[c][r]
#pragma unroll
    for (int e = 0; e < 64; e++) { int id = t + e * 256; Wb[id] = g1[id]; }
    {
        int n = (nkbase + r0) >> 4;
        const float* qrow = q + ((size_t)b * NPTS + n) * 128 + c0;
#pragma unroll
        for (int i = 0; i < 4; i++) {
            int j = jrow[r0 + i];
            const float* krow = xk + ((size_t)b * NPTS + j) * 128 + c0;
#pragma unroll
            for (int jj = 0; jj < 16; jj++) {
                float h = pos[i][jj] + qrow[jj] - krow[jj];
                Ab[(c0 + jj) * 129 + (r0 + i)] = h;
            }
        }
    }
    __syncthreads();

    // u = relu(h @ g1 + bg1)
    float acc[4][16];
#pragma unroll
    for (int i = 0; i < 4; i++)
#pragma unroll
        for (int j = 0; j < 16; j++) acc[i][j] = bg1s[c0 + j];
#pragma unroll 4
    for (int kk = 0; kk < 128; ++kk) {
        float a0 = Ab[kk * 129 + r0 + 0];
        float a1 = Ab[kk * 129 + r0 + 1];
        float a2 = Ab[kk * 129 + r0 + 2];
        float a3 = Ab[kk * 129 + r0 + 3];
        const float4 w0 = *(const float4*)&Wb[kk * 128 + c0];
        const float4 w1 = *(const float4*)&Wb[kk * 128 + c0 + 4];
        const float4 w2 = *(const float4*)&Wb[kk * 128 + c0 + 8];
        const float4 w3 = *(const float4*)&Wb[kk * 128 + c0 + 12];
        float wj[16] = {w0.x, w0.y, w0.z, w0.w, w1.x, w1.y, w1.z, w1.w,
                        w2.x, w2.y, w2.z, w2.w, w3.x, w3.y, w3.z, w3.w};
#pragma unroll
        for (int j = 0; j < 16; j++) {
            acc[0][j] += a0 * wj[j];
            acc[1][j] += a1 * wj[j];
            acc[2][j] += a2 * wj[j];
            acc[3][j] += a3 * wj[j];
        }
    }
#pragma unroll
    for (int i = 0; i < 4; i++)
#pragma unroll
        for (int j = 0; j < 16; j++)
            uout[(size_t)(R0 + r0 + i) * 128 + c0 + j] = fmaxf(acc[i][j], 0.0f);
}

// ---------------------------------------------------------------- logits = u@g2+b, softmax over k, in-place in attn region
__global__ __launch_bounds__(256, 1) void k4_kernel(const float* __restrict__ g2,
                                                    const float* __restrict__ bg2,
                                                    float* __restrict__ attn) {
    __shared__ float Ab[128 * 129];
    __shared__ __align__(16) float Wb[128 * 128];
    __shared__ float bg2s[128];
    const int t = threadIdx.x;
    const int R0 = blockIdx.x * 128;
#pragma unroll
    for (int e = 0; e < 64; e++) {
        int id = t + e * 256;
        int r = id >> 7, c = id & 127;
        Ab[c * 129 + r] = attn[(size_t)(R0 + r) * 128 + c];
    }
#pragma unroll
    for (int e = 0; e < 64; e++) { int id = t + e * 256; Wb[id] = g2[id]; }
    if (t < 128) bg2s[t] = bg2[t];
    __syncthreads();

    const int r0 = (t >> 3) * 4;
    const int c0 = (t & 7) * 16;
    float acc[4][16];
#pragma unroll
    for (int i = 0; i < 4; i++)
#pragma unroll
        for (int j = 0; j < 16; j++) acc[i][j] = bg2s[c0 + j];
#pragma unroll 4
    for (int kk = 0; kk < 128; ++kk) {
        float a0 = Ab[kk * 129 + r0 + 0];
        float a1 = Ab[kk * 129 + r0 + 1];
        float a2 = Ab[kk * 129 + r0 + 2];
        float a3 = Ab[kk * 129 + r0 + 3];
        const float4 w0 = *(const float4*)&Wb[kk * 128 + c0];
        const float4 w1 = *(const float4*)&Wb[kk * 128 + c0 + 4];
        const float4 w2 = *(const float4*)&Wb[kk * 128 + c0 + 8];
        const float4 w3 = *(const float4*)&Wb[kk * 128 + c0 + 12];
        float wj[16] = {w0.x, w0.y, w0.z, w0.w, w1.x, w1.y, w1.z, w1.w,
                        w2.x, w2.y, w2.z, w2.w, w3.x, w3.y, w3.z, w3.w};
#pragma unroll
        for (int j = 0; j < 16; j++) {
            acc[0][j] += a0 * wj[j];
            acc[1][j] += a1 * wj[j];
            acc[2][j] += a2 * wj[j];
            acc[3][j] += a3 * wj[j];
        }
    }
    const float scale = 0.08838834764831845f; /* 1/sqrt(128) */
    __syncthreads();
#pragma unroll
    for (int i = 0; i < 4; i++)
#pragma unroll
        for (int j = 0; j < 16; j++)
            Ab[(c0 + j) * 129 + (r0 + i)] = acc[i][j] * scale;
    __syncthreads();

    // softmax over the 16 neighbors for each (n_local, channel)
#pragma unroll
    for (int e = 0; e < 4; e++) {
        int p = t + e * 256;
        int n = p >> 7, c = p & 127;
        float* col = &Ab[c * 129 + n * 16];
        float mx = col[0];
#pragma unroll
        for (int k = 1; k < 16; k++) mx = fmaxf(mx, col[k]);
        float ex[16];
        float s = 0.0f;
#pragma unroll
        for (int k = 0; k < 16; k++) { ex[k] = expf(col[k] - mx); s += ex[k]; }
        float inv = 1.0f / s;
#pragma unroll
        for (int k = 0; k < 16; k++) col[k] = ex[k] * inv;
    }
    __syncthreads();
#pragma unroll
    for (int e = 0; e < 64; e++) {
        int id = t + e * 256;
        int r = id >> 7, c = id & 127;
        attn[(size_t)(R0 + r) * 128 + c] = Ab[c * 129 + r];
    }
}

// ---------------------------------------------------------------- res_pre = sum_k attn*(v_nbr + pos)  (pos recomputed)
__global__ __launch_bounds__(256, 1) void k5_kernel(const float* __restrict__ xyz,
                                                    const int* __restrict__ idxw,
                                                    const float* __restrict__ xv,
                                                    const float* __restrict__ d1,
                                                    const float* __restrict__ bd1,
                                                    const float* __restrict__ d2,
                                                    const float* __restrict__ bd2,
                                                    const float* __restrict__ attn,
                                                    float* __restrict__ res_pre) {
    __shared__ float Ab[128 * 129];
    __shared__ __align__(16) float Wb[128 * 128];
    __shared__ float d1s[3 * 128];
    __shared__ float bd1s[128], bd2s[128];
    __shared__ float rels[128 * 3];
    __shared__ int jrow[128];
    __shared__ float part[4][8][128];

    const int t = threadIdx.x;
    const int R0 = blockIdx.x * 128;
    const int b = R0 >> 17;
    const int nkbase = R0 & 131071;

#pragma unroll
    for (int e = 0; e < 2; e++) { int id = t + e * 256; if (id < 384) d1s[id] = d1[id]; }
    if (t < 128) { bd1s[t] = bd1[t]; bd2s[t] = bd2[t]; }
    if (t < 128) {
        int nk = nkbase + t;
        int n = nk >> 4;
        int j = idxw[R0 + t];
        jrow[t] = j;
        const float* pn = xyz + ((size_t)b * NPTS + n) * 3;
        const float* pj = xyz + ((size_t)b * NPTS + j) * 3;
        rels[t * 3 + 0] = pn[0] - pj[0];
        rels[t * 3 + 1] = pn[1] - pj[1];
        rels[t * 3 + 2] = pn[2] - pj[2];
    }
#pragma unroll
    for (int e = 0; e < 64; e++) { int id = t + e * 256; Wb[id] = d2[id]; }
    __syncthreads();

    {
        const int r = t & 127;
        const float rx = rels[r * 3 + 0], ry = rels[r * 3 + 1], rz = rels[r * 3 + 2];
#pragma unroll
        for (int e = 0; e < 64; e++) {
            int c = (t >> 7) + e * 2;
            float v = rx * d1s[c] + ry * d1s[128 + c] + rz * d1s[256 + c] + bd1s[c];
            Ab[c * 129 + r] = fmaxf(v, 0.0f);
        }
    }
    __syncthreads();

    const int r0 = (t >> 3) * 4;
    const int c0 = (t & 7) * 16;
    float pos[4][16];
#pragma unroll
    for (int i = 0; i < 4; i++)
#pragma unroll
        for (int j = 0; j < 16; j++) pos[i][j] = bd2s[c0 + j];
#pragma unroll 4
    for (int kk = 0; kk < 128; ++kk) {
        float a0 = Ab[kk * 129 + r0 + 0];
        float a1 = Ab[kk * 129 + r0 + 1];
        float a2 = Ab[kk * 129 + r0 + 2];
        float a3 = Ab[kk * 129 + r0 + 3];
        const float4 w0 = *(const float4*)&Wb[kk * 128 + c0];
        const float4 w1 = *(const float4*)&Wb[kk * 128 + c0 + 4];
        const float4 w2 = *(const float4*)&Wb[kk * 128 + c0 + 8];
        const float4 w3 = *(const float4*)&Wb[kk * 128 + c0 + 12];
        float wj[16] = {w0.x, w0.y, w0.z, w0.w, w1.x, w1.y, w1.z, w1.w,
                        w2.x, w2.y, w2.z, w2.w, w3.x, w3.y, w3.z, w3.w};
#pragma unroll
        for (int j = 0; j < 16; j++) {
            pos[0][j] += a0 * wj[j];
            pos[1][j] += a1 * wj[j];
            pos[2][j] += a2 * wj[j];
            pos[3][j] += a3 * wj[j];
        }
    }
#pragma unroll
    for (int i = 0; i < 4; i++)
#pragma unroll
        for (int j = 0; j < 16; j++) pos[i][j] = fmaxf(pos[i][j], 0.0f);

    float partial[16];
#pragma unroll
    for (int j = 0; j < 16; j++) partial[j] = 0.0f;
#pragma unroll
    for (int i = 0; i < 4; i++) {
        const float* arow = attn + (size_t)(R0 + r0 + i) * 128 + c0;
        int j = jrow[r0 + i];
        const float* vrow = xv + ((size_t)b * NPTS + j) * 128 + c0;
#pragma unroll
        for (int jj = 0; jj < 16; jj++)
            partial[jj] += arow[jj] * (vrow[jj] + pos[i][jj]);
    }
    const int slot = (r0 >> 2) & 3;
    const int nl = r0 >> 4;
#pragma unroll
    for (int jj = 0; jj < 16; jj++) part[slot][nl][c0 + jj] = partial[jj];
    __syncthreads();
#pragma unroll
    for (int e = 0; e < 4; e++) {
        int p = t + e * 256;
        int n = p >> 7, c = p & 127;
        float s = ((part[0][n][c] + part[1][n][c]) + part[2][n][c]) + part[3][n][c];
        res_pre[(size_t)((R0 >> 4) + n) * 128 + c] = s;
    }
}

// ---------------------------------------------------------------- res = res_pre@fc2 + b + features
__global__ __launch_bounds__(256, 1) void k6_kernel(const float* __restrict__ res_pre,
                                                    const float* __restrict__ w,
                                                    const float* __restrict__ bias,
                                                    const float* __restrict__ feats,
                                                    float* __restrict__ res_out) {
    __shared__ float At[128 * 65];
    __shared__ __align__(16) float Wt[128 * 64];
    const int t = threadIdx.x;
    const int base = blockIdx.x * 64;
#pragma unroll
    for (int e = 0; e < 32; e++) {
        int id = t + e * 256;
        int r = id >> 7, c = id & 127;
        At[c * 65 + r] = res_pre[(size_t)(base + r) * 128 + c];
    }
#pragma unroll
    for (int e = 0; e < 32; e++) { int id = t + e * 256; Wt[id] = w[id]; }
    __syncthreads();
    const int r0 = (t >> 4) * 4;
    const int c0 = (t & 15) * 4;
    float acc[4][4];
#pragma unroll
    for (int i = 0; i < 4; i++)
#pragma unroll
        for (int j = 0; j < 4; j++) acc[i][j] = bias[c0 + j];
#pragma unroll 4
    for (int kk = 0; kk < 128; ++kk) {
        float a0 = At[kk * 65 + r0 + 0];
        float a1 = At[kk * 65 + r0 + 1];
        float a2 = At[kk * 65 + r0 + 2];
        float a3 = At[kk * 65 + r0 + 3];
        const float4 w0 = *(const float4*)&Wt[kk * 64 + c0];
        float wj[4] = {w0.x, w0.y, w0.z, w0.w};
#pragma unroll
        for (int j = 0; j < 4; j++) {
            acc[0][j] += a0 * wj[j];
            acc[1][j] += a1 * wj[j];
            acc[2][j] += a2 * wj[j];
            acc[3][j] += a3 * wj[j];
        }
    }
#pragma unroll
    for (int i = 0; i < 4; i++)
#pragma unroll
        for (int j = 0; j < 4; j++)
            res_out[(size_t)(base + r0 + i) * 64 + c0 + j] =
                acc[i][j] + feats[(size_t)(base + r0 + i) * 64 + c0 + j];
}

extern "C" void kernel_launch(void* const* d_in, const int* in_sizes, int n_in,
                              void* d_out, int out_size, void* d_ws, size_t ws_size,
                              hipStream_t stream) {
    (void)in_sizes; (void)n_in; (void)out_size; (void)ws_size;
    const float* xyz   = (const float*)d_in[0];
    const float* feats = (const float*)d_in[2];
    const float* fc1_w = (const float*)d_in[3];
    const float* fc1_b = (const float*)d_in[4];
    const float* fc2_w = (const float*)d_in[5];
    const float* fc2_b = (const float*)d_in[6];
    const float* g1    = (const float*)d_in[7];
    const float* bg1   = (const float*)d_in[8];
    const float* g2    = (const float*)d_in[9];
    const float* bg2   = (const float*)d_in[10];
    const float* d1    = (const float*)d_in[11];
    const float* bd1   = (const float*)d_in[12];
    const float* d2    = (const float*)d_in[13];
    const float* bd2   = (const float*)d_in[14];
    const float* wq    = (const float*)d_in[15];
    const float* wk    = (const float*)d_in[16];
    const float* wv    = (const float*)d_in[17];

    int* idxw   = (int*)d_ws;
    float* xbuf = (float*)((char*)d_ws + (1 << 20));
    float* qbuf = xbuf + 2097152;
    float* kbuf = qbuf + 2097152;
    float* vbuf = kbuf + 2097152;
    float* rpre = vbuf + 2097152;

    float* res_out = (float*)d_out;
    float* attn    = res_out + 1048576;  /* u lives here between k3 and k4 */

    knn_kernel<<<4096, 256, 0, stream>>>(xyz, idxw);
    gemm_x_kernel<<<256, 256, 0, stream>>>(feats, fc1_w, fc1_b, xbuf);
    gemm_qkv_kernel<<<dim3(256, 3), 256, 0, stream>>>(xbuf, wq, wk, wv, qbuf, kbuf, vbuf);
    k3_kernel<<<2048, 256, 0, stream>>>(xyz, idxw, qbuf, kbuf, d1, bd1, d2, bd2, g1, bg1, attn);
    k4_kernel<<<2048, 256, 0, stream>>>(g2, bg2, attn);
    k5_kernel<<<2048, 256, 0, stream>>>(xyz, idxw, vbuf, d1, bd1, d2, bd2, attn, rpre);
    k6_kernel<<<256, 256, 0, stream>>>(rpre, fc2_w, fc2_b, feats, res_out);
}

// Round 3
// 372.298 us; speedup vs baseline: 3.0437x; 2.4685x over previous
//
#include <hip/hip_runtime.h>
#include <cstdint>

typedef unsigned long long ull;
typedef __bf16 bf16x8 __attribute__((ext_vector_type(8)));
typedef float f32x4 __attribute__((ext_vector_type(4)));

#define NPTS 8192
#define NB 2
#define KNN 16
#define DM 128
#define PADK 136

__device__ __forceinline__ float sq3f(float x, float y, float z) {
    return __fadd_rn(__fadd_rn(__fmul_rn(x, x), __fmul_rn(y, y)), __fmul_rn(z, z));
}
__device__ __forceinline__ float dot3f(float ax, float ay, float az, float bx, float by, float bz) {
    return __fadd_rn(__fadd_rn(__fmul_rn(ax, bx), __fmul_rn(ay, by)), __fmul_rn(az, bz));
}
__device__ __forceinline__ unsigned ford(float f) {
    unsigned u = __float_as_uint(f);
    return (u & 0x80000000u) ? ~u : (u | 0x80000000u);
}

// ---------------------------------------------------------------- KNN (unchanged)
__global__ __launch_bounds__(256) void knn_kernel(const float* __restrict__ xyz,
                                                  int* __restrict__ idx_out) {
    __shared__ float xs[1024 * 3];
    __shared__ float sj[1024];
    const int t = threadIdx.x;
    const int wv = t >> 6, lane = t & 63;
    const int q_id = blockIdx.x * 4 + wv;
    const int b = q_id >> 13;
    const int i = q_id & (NPTS - 1);
    const float* xb = xyz + (size_t)b * NPTS * 3;
    const float qx = xb[3 * i + 0], qy = xb[3 * i + 1], qz = xb[3 * i + 2];
    const float sqi = sq3f(qx, qy, qz);

    ull list = ~0ull;
    ull thr = ~0ull;

    for (int ch = 0; ch < 8; ++ch) {
        __syncthreads();
#pragma unroll
        for (int e = 0; e < 12; e++) {
            int id = t + e * 256;
            xs[id] = xb[ch * 3072 + id];
        }
        __syncthreads();
#pragma unroll
        for (int e = 0; e < 4; e++) {
            int jl = t + e * 256;
            sj[jl] = sq3f(xs[3 * jl + 0], xs[3 * jl + 1], xs[3 * jl + 2]);
        }
        __syncthreads();
#pragma unroll 2
        for (int m = 0; m < 16; m++) {
            int jl = m * 64 + lane;
            int j = ch * 1024 + jl;
            float px = xs[3 * jl + 0], py = xs[3 * jl + 1], pz = xs[3 * jl + 2];
            float d = __fsub_rn(__fadd_rn(sqi, sj[jl]),
                                __fmul_rn(2.0f, dot3f(qx, qy, qz, px, py, pz)));
            ull key = ((ull)ford(d) << 32) | (unsigned)j;
            ull ballot = __ballot(key < thr);
            if (ballot == 0ull) continue;
            do {
                int l = __builtin_ctzll(ballot);
                ballot &= ballot - 1;
                ull ck = __shfl(key, l);
                ull prev = __shfl_up(list, 1);
                bool shift = (ck < list);
                list = shift ? ((lane == 0 || ck >= prev) ? ck : prev) : list;
            } while (ballot);
            thr = __shfl(list, 15);
        }
    }
    if (lane < 16)
        idx_out[q_id * 16 + lane] = (int)(unsigned)(list & 0xffffffffu);
}

// ---------------------------------------------------------------- weight prep: f32 [k][n] -> bf16 [n][k]
__global__ __launch_bounds__(256) void wprep_kernel(const float* __restrict__ d2,
                                                    const float* __restrict__ g1,
                                                    const float* __restrict__ g2,
                                                    __bf16* __restrict__ d2t,
                                                    __bf16* __restrict__ g1t,
                                                    __bf16* __restrict__ g2t) {
    const float* src = (blockIdx.x == 0) ? d2 : ((blockIdx.x == 1) ? g1 : g2);
    __bf16* dst = (blockIdx.x == 0) ? d2t : ((blockIdx.x == 1) ? g1t : g2t);
#pragma unroll
    for (int e = 0; e < 64; e++) {
        int id = threadIdx.x + e * 256;
        int k = id >> 7, n = id & 127;
        dst[n * 128 + k] = (__bf16)src[id];
    }
}

// ---------------------------------------------------------------- x = features@fc1 + b (unchanged)
__global__ __launch_bounds__(256, 1) void gemm_x_kernel(const float* __restrict__ feats,
                                                        const float* __restrict__ w,
                                                        const float* __restrict__ bias,
                                                        float* __restrict__ xout) {
    __shared__ float At[64 * 65];
    __shared__ __align__(16) float Wt[64 * 128];
    const int t = threadIdx.x;
    const int base = blockIdx.x * 64;
#pragma unroll
    for (int e = 0; e < 16; e++) {
        int id = t + e * 256;
        int r = id >> 6, c = id & 63;
        At[c * 65 + r] = feats[(size_t)(base + r) * 64 + c];
    }
#pragma unroll
    for (int e = 0; e < 32; e++) { int id = t + e * 256; Wt[id] = w[id]; }
    __syncthreads();
    const int r0 = (t >> 4) * 4;
    const int c0 = (t & 15) * 8;
    float acc[4][8];
#pragma unroll
    for (int i = 0; i < 4; i++)
#pragma unroll
        for (int j = 0; j < 8; j++) acc[i][j] = bias[c0 + j];
#pragma unroll 4
    for (int kk = 0; kk < 64; ++kk) {
        float a0 = At[kk * 65 + r0 + 0];
        float a1 = At[kk * 65 + r0 + 1];
        float a2 = At[kk * 65 + r0 + 2];
        float a3 = At[kk * 65 + r0 + 3];
        const float4 w0 = *(const float4*)&Wt[kk * 128 + c0];
        const float4 w1 = *(const float4*)&Wt[kk * 128 + c0 + 4];
        float wj[8] = {w0.x, w0.y, w0.z, w0.w, w1.x, w1.y, w1.z, w1.w};
#pragma unroll
        for (int j = 0; j < 8; j++) {
            acc[0][j] += a0 * wj[j];
            acc[1][j] += a1 * wj[j];
            acc[2][j] += a2 * wj[j];
            acc[3][j] += a3 * wj[j];
        }
    }
#pragma unroll
    for (int i = 0; i < 4; i++)
#pragma unroll
        for (int j = 0; j < 8; j++)
            xout[(size_t)(base + r0 + i) * 128 + c0 + j] = acc[i][j];
}

// ---------------------------------------------------------------- q/xk/xv = x@W (unchanged)
__global__ __launch_bounds__(256, 1) void gemm_qkv_kernel(const float* __restrict__ x,
                                                          const float* __restrict__ wq,
                                                          const float* __restrict__ wk,
                                                          const float* __restrict__ wv,
                                                          float* __restrict__ qo,
                                                          float* __restrict__ ko,
                                                          float* __restrict__ vo) {
    const float* w = (blockIdx.y == 0) ? wq : ((blockIdx.y == 1) ? wk : wv);
    float* o = (blockIdx.y == 0) ? qo : ((blockIdx.y == 1) ? ko : vo);
    __shared__ float At[128 * 65];
    __shared__ __align__(16) float Wt[128 * 128];
    const int t = threadIdx.x;
    const int base = blockIdx.x * 64;
#pragma unroll
    for (int e = 0; e < 32; e++) {
        int id = t + e * 256;
        int r = id >> 7, c = id & 127;
        At[c * 65 + r] = x[(size_t)(base + r) * 128 + c];
    }
#pragma unroll
    for (int e = 0; e < 64; e++) { int id = t + e * 256; Wt[id] = w[id]; }
    __syncthreads();
    const int r0 = (t >> 4) * 4;
    const int c0 = (t & 15) * 8;
    float acc[4][8];
#pragma unroll
    for (int i = 0; i < 4; i++)
#pragma unroll
        for (int j = 0; j < 8; j++) acc[i][j] = 0.0f;
#pragma unroll 4
    for (int kk = 0; kk < 128; ++kk) {
        float a0 = At[kk * 65 + r0 + 0];
        float a1 = At[kk * 65 + r0 + 1];
        float a2 = At[kk * 65 + r0 + 2];
        float a3 = At[kk * 65 + r0 + 3];
        const float4 w0 = *(const float4*)&Wt[kk * 128 + c0];
        const float4 w1 = *(const float4*)&Wt[kk * 128 + c0 + 4];
        float wj[8] = {w0.x, w0.y, w0.z, w0.w, w1.x, w1.y, w1.z, w1.w};
#pragma unroll
        for (int j = 0; j < 8; j++) {
            acc[0][j] += a0 * wj[j];
            acc[1][j] += a1 * wj[j];
            acc[2][j] += a2 * wj[j];
            acc[3][j] += a3 * wj[j];
        }
    }
#pragma unroll
    for (int i = 0; i < 4; i++)
#pragma unroll
        for (int j = 0; j < 8; j++)
            o[(size_t)(base + r0 + i) * 128 + c0 + j] = acc[i][j];
}

// MFMA K-loop over K=128: contiguous-8-per-lane fragments (m91/m92-verified convention)
#define DO_GEMM(ACC0, ACC1, WPTR)                                                          \
    {                                                                                      \
        _Pragma("unroll")                                                                  \
        for (int kt = 0; kt < 4; kt++) {                                                   \
            const int ko = kt * 32 + 8 * lg;                                               \
            bf16x8 a0 = *(const bf16x8*)&Ab[(rbase + lr) * PADK + ko];                     \
            bf16x8 a1 = *(const bf16x8*)&Ab[(rbase + 16 + lr) * PADK + ko];                \
            _Pragma("unroll")                                                              \
            for (int ct = 0; ct < 8; ct++) {                                               \
                bf16x8 bv = *(const bf16x8*)&WPTR[(ct * 16 + lr) * PADK + ko];             \
                ACC0[ct] = __builtin_amdgcn_mfma_f32_16x16x32_bf16(a0, bv, ACC0[ct], 0, 0, 0); \
                ACC1[ct] = __builtin_amdgcn_mfma_f32_16x16x32_bf16(a1, bv, ACC1[ct], 0, 0, 0); \
            }                                                                              \
        }                                                                                  \
    }

#define STAGE_W(SRC)                                                                       \
    {                                                                                      \
        _Pragma("unroll")                                                                  \
        for (int e = 0; e < 8; e++) {                                                      \
            int ch = t + e * 256;                                                          \
            int r = ch >> 4, ck = ch & 15;                                                 \
            *(bf16x8*)&Wb[r * PADK + ck * 8] = *(const bf16x8*)&SRC[r * 128 + ck * 8];     \
        }                                                                                  \
    }

// ---------------------------------------------------------------- fused k3+k4:
// T=relu(rel@d1+b) -> pos=relu(T@d2+b) -> h=q-k+pos -> u=relu(h@g1+b)
// -> logits=u@g2+b -> softmax(over 16 neighbors) -> attn  (all GEMMs MFMA bf16)
__global__ __launch_bounds__(256, 2) void k34_kernel(const float* __restrict__ xyz,
                                                     const int* __restrict__ idxw,
                                                     const float* __restrict__ q,
                                                     const float* __restrict__ xk,
                                                     const float* __restrict__ d1,
                                                     const float* __restrict__ bd1,
                                                     const float* __restrict__ bd2,
                                                     const float* __restrict__ bg1,
                                                     const float* __restrict__ bg2,
                                                     const __bf16* __restrict__ d2t,
                                                     const __bf16* __restrict__ g1t,
                                                     const __bf16* __restrict__ g2t,
                                                     float* __restrict__ attn) {
    __shared__ __bf16 Ab[128 * PADK];
    __shared__ __bf16 Wb[128 * PADK];
    __shared__ float rels[128 * 4];
    __shared__ int jrow[128];
    __shared__ float d1s[3 * 128];
    __shared__ float bd1s[128], bd2s[128], bg1s[128], bg2s[128];

    const int t = threadIdx.x;
    const int wv = t >> 6;
    const int lane = t & 63;
    const int lr = lane & 15, lg = lane >> 4;
    const int R0 = blockIdx.x * 128;
    const int b = R0 >> 17;
    const int rbase = wv * 32;

#pragma unroll
    for (int e = 0; e < 2; e++) { int id = t + e * 256; if (id < 384) d1s[id] = d1[id]; }
    if (t < 128) {
        bd1s[t] = bd1[t]; bd2s[t] = bd2[t]; bg1s[t] = bg1[t]; bg2s[t] = bg2[t];
    } else {
        int r = t - 128;
        int j = idxw[R0 + r];
        jrow[r] = j;
        const float* pn = xyz + (size_t)((R0 + r) >> 4) * 3;
        const float* pj = xyz + (size_t)((b << 13) + j) * 3;
        rels[r * 4 + 0] = pn[0] - pj[0];
        rels[r * 4 + 1] = pn[1] - pj[1];
        rels[r * 4 + 2] = pn[2] - pj[2];
    }
    STAGE_W(d2t)
    __syncthreads();

    // T = relu(rel@d1 + bd1) -> Ab (bf16)
    {
        const int c = t & 127;
        const float w0 = d1s[c], w1 = d1s[128 + c], w2 = d1s[256 + c], bb = bd1s[c];
#pragma unroll
        for (int e = 0; e < 64; e++) {
            int r = (t >> 7) + e * 2;
            float v = fmaf(rels[r * 4 + 2], w2,
                      fmaf(rels[r * 4 + 1], w1, fmaf(rels[r * 4 + 0], w0, bb)));
            Ab[r * PADK + c] = (__bf16)fmaxf(v, 0.0f);
        }
    }
    __syncthreads();

    // GEMM1: pos = T@d2 + bd2 (relu applied when consumed)
    f32x4 acc0[8], acc1[8];
#pragma unroll
    for (int ct = 0; ct < 8; ct++) {
        float bb = bd2s[ct * 16 + lr];
        acc0[ct] = (f32x4){bb, bb, bb, bb};
        acc1[ct] = acc0[ct];
    }
    DO_GEMM(acc0, acc1, Wb)

    // h = relu(pos) + q - k_nbr  -> Ab (bf16)   [own rows only: no barrier needed first]
#pragma unroll
    for (int rt = 0; rt < 2; rt++) {
        const int rloc = rbase + rt * 16 + 4 * lg;
        const size_t qbase = (size_t)((R0 + rloc) >> 4) * 128;
        const int j0 = jrow[rloc + 0], j1 = jrow[rloc + 1];
        const int j2 = jrow[rloc + 2], j3 = jrow[rloc + 3];
        const size_t kb0 = (size_t)((b << 13) + j0) * 128;
        const size_t kb1 = (size_t)((b << 13) + j1) * 128;
        const size_t kb2 = (size_t)((b << 13) + j2) * 128;
        const size_t kb3 = (size_t)((b << 13) + j3) * 128;
        f32x4* accR = rt ? acc1 : acc0;
#pragma unroll
        for (int ct = 0; ct < 8; ct++) {
            const int c = ct * 16 + lr;
            const float qv = q[qbase + c];
            f32x4 p = accR[ct];
            Ab[(rloc + 0) * PADK + c] = (__bf16)(fmaxf(p[0], 0.0f) + qv - xk[kb0 + c]);
            Ab[(rloc + 1) * PADK + c] = (__bf16)(fmaxf(p[1], 0.0f) + qv - xk[kb1 + c]);
            Ab[(rloc + 2) * PADK + c] = (__bf16)(fmaxf(p[2], 0.0f) + qv - xk[kb2 + c]);
            Ab[(rloc + 3) * PADK + c] = (__bf16)(fmaxf(p[3], 0.0f) + qv - xk[kb3 + c]);
        }
    }
    __syncthreads();
    STAGE_W(g1t)
    __syncthreads();

    // GEMM2: u = relu(h@g1 + bg1) -> Ab (bf16)
#pragma unroll
    for (int ct = 0; ct < 8; ct++) {
        float bb = bg1s[ct * 16 + lr];
        acc0[ct] = (f32x4){bb, bb, bb, bb};
        acc1[ct] = acc0[ct];
    }
    DO_GEMM(acc0, acc1, Wb)
#pragma unroll
    for (int rt = 0; rt < 2; rt++) {
        const int rloc = rbase + rt * 16 + 4 * lg;
        f32x4* accR = rt ? acc1 : acc0;
#pragma unroll
        for (int ct = 0; ct < 8; ct++) {
            const int c = ct * 16 + lr;
            f32x4 p = accR[ct];
            Ab[(rloc + 0) * PADK + c] = (__bf16)fmaxf(p[0], 0.0f);
            Ab[(rloc + 1) * PADK + c] = (__bf16)fmaxf(p[1], 0.0f);
            Ab[(rloc + 2) * PADK + c] = (__bf16)fmaxf(p[2], 0.0f);
            Ab[(rloc + 3) * PADK + c] = (__bf16)fmaxf(p[3], 0.0f);
        }
    }
    __syncthreads();
    STAGE_W(g2t)
    __syncthreads();

    // GEMM3: logits = u@g2 + bg2 ; scale ; softmax over 16 neighbors ; write attn
#pragma unroll
    for (int ct = 0; ct < 8; ct++) {
        float bb = bg2s[ct * 16 + lr];
        acc0[ct] = (f32x4){bb, bb, bb, bb};
        acc1[ct] = acc0[ct];
    }
    DO_GEMM(acc0, acc1, Wb)
    const float scale = 0.08838834764831845f; /* 1/sqrt(128) */
#pragma unroll
    for (int rt = 0; rt < 2; rt++) {
        const int rloc = rbase + rt * 16 + 4 * lg;
        f32x4* accR = rt ? acc1 : acc0;
#pragma unroll
        for (int ct = 0; ct < 8; ct++) {
            const int c = ct * 16 + lr;
            f32x4 p = accR[ct];
            float l0 = p[0] * scale, l1 = p[1] * scale, l2 = p[2] * scale, l3 = p[3] * scale;
            float m = fmaxf(fmaxf(l0, l1), fmaxf(l2, l3));
            m = fmaxf(m, __shfl_xor(m, 16));
            m = fmaxf(m, __shfl_xor(m, 32));
            float e0 = __expf(l0 - m), e1 = __expf(l1 - m);
            float e2 = __expf(l2 - m), e3 = __expf(l3 - m);
            float s = (e0 + e1) + (e2 + e3);
            s += __shfl_xor(s, 16);
            s += __shfl_xor(s, 32);
            float inv = 1.0f / s;
            size_t ob = (size_t)(R0 + rloc) * 128 + c;
            attn[ob + 0 * 128] = e0 * inv;
            attn[ob + 1 * 128] = e1 * inv;
            attn[ob + 2 * 128] = e2 * inv;
            attn[ob + 3 * 128] = e3 * inv;
        }
    }
}

// ---------------------------------------------------------------- k5: pos (MFMA) + res_pre = sum_k attn*(v+pos)
__global__ __launch_bounds__(256, 2) void k5_kernel(const float* __restrict__ xyz,
                                                    const int* __restrict__ idxw,
                                                    const float* __restrict__ xv,
                                                    const float* __restrict__ d1,
                                                    const float* __restrict__ bd1,
                                                    const float* __restrict__ bd2,
                                                    const __bf16* __restrict__ d2t,
                                                    const float* __restrict__ attn,
                                                    float* __restrict__ res_pre) {
    __shared__ __bf16 Ab[128 * PADK];
    __shared__ __bf16 Wb[128 * PADK];
    __shared__ float rels[128 * 4];
    __shared__ int jrow[128];
    __shared__ float d1s[3 * 128];
    __shared__ float bd1s[128], bd2s[128];

    const int t = threadIdx.x;
    const int wv = t >> 6;
    const int lane = t & 63;
    const int lr = lane & 15, lg = lane >> 4;
    const int R0 = blockIdx.x * 128;
    const int b = R0 >> 17;
    const int rbase = wv * 32;

#pragma unroll
    for (int e = 0; e < 2; e++) { int id = t + e * 256; if (id < 384) d1s[id] = d1[id]; }
    if (t < 128) {
        bd1s[t] = bd1[t]; bd2s[t] = bd2[t];
    } else {
        int r = t - 128;
        int j = idxw[R0 + r];
        jrow[r] = j;
        const float* pn = xyz + (size_t)((R0 + r) >> 4) * 3;
        const float* pj = xyz + (size_t)((b << 13) + j) * 3;
        rels[r * 4 + 0] = pn[0] - pj[0];
        rels[r * 4 + 1] = pn[1] - pj[1];
        rels[r * 4 + 2] = pn[2] - pj[2];
    }
    STAGE_W(d2t)
    __syncthreads();

    {
        const int c = t & 127;
        const float w0 = d1s[c], w1 = d1s[128 + c], w2 = d1s[256 + c], bb = bd1s[c];
#pragma unroll
        for (int e = 0; e < 64; e++) {
            int r = (t >> 7) + e * 2;
            float v = fmaf(rels[r * 4 + 2], w2,
                      fmaf(rels[r * 4 + 1], w1, fmaf(rels[r * 4 + 0], w0, bb)));
            Ab[r * PADK + c] = (__bf16)fmaxf(v, 0.0f);
        }
    }
    __syncthreads();

    f32x4 acc0[8], acc1[8];
#pragma unroll
    for (int ct = 0; ct < 8; ct++) {
        float bb = bd2s[ct * 16 + lr];
        acc0[ct] = (f32x4){bb, bb, bb, bb};
        acc1[ct] = acc0[ct];
    }
    DO_GEMM(acc0, acc1, Wb)

#pragma unroll
    for (int rt = 0; rt < 2; rt++) {
        const int rloc = rbase + rt * 16 + 4 * lg;
        const int j0 = jrow[rloc + 0], j1 = jrow[rloc + 1];
        const int j2 = jrow[rloc + 2], j3 = jrow[rloc + 3];
        const size_t vb0 = (size_t)((b << 13) + j0) * 128;
        const size_t vb1 = (size_t)((b << 13) + j1) * 128;
        const size_t vb2 = (size_t)((b << 13) + j2) * 128;
        const size_t vb3 = (size_t)((b << 13) + j3) * 128;
        const size_t ab = (size_t)(R0 + rloc) * 128;
        f32x4* accR = rt ? acc1 : acc0;
#pragma unroll
        for (int ct = 0; ct < 8; ct++) {
            const int c = ct * 16 + lr;
            f32x4 p = accR[ct];
            float s = attn[ab + 0 * 128 + c] * (xv[vb0 + c] + fmaxf(p[0], 0.0f))
                    + attn[ab + 1 * 128 + c] * (xv[vb1 + c] + fmaxf(p[1], 0.0f))
                    + attn[ab + 2 * 128 + c] * (xv[vb2 + c] + fmaxf(p[2], 0.0f))
                    + attn[ab + 3 * 128 + c] * (xv[vb3 + c] + fmaxf(p[3], 0.0f));
            s += __shfl_xor(s, 16);
            s += __shfl_xor(s, 32);
            if (lg == 0)
                res_pre[(size_t)((R0 >> 4) + wv * 2 + rt) * 128 + c] = s;
        }
    }
}

// ---------------------------------------------------------------- res = res_pre@fc2 + b + features (unchanged)
__global__ __launch_bounds__(256, 1) void k6_kernel(const float* __restrict__ res_pre,
                                                    const float* __restrict__ w,
                                                    const float* __restrict__ bias,
                                                    const float* __restrict__ feats,
                                                    float* __restrict__ res_out) {
    __shared__ float At[128 * 65];
    __shared__ __align__(16) float Wt[128 * 64];
    const int t = threadIdx.x;
    const int base = blockIdx.x * 64;
#pragma unroll
    for (int e = 0; e < 32; e++) {
        int id = t + e * 256;
        int r = id >> 7, c = id & 127;
        At[c * 65 + r] = res_pre[(size_t)(base + r) * 128 + c];
    }
#pragma unroll
    for (int e = 0; e < 32; e++) { int id = t + e * 256; Wt[id] = w[id]; }
    __syncthreads();
    const int r0 = (t >> 4) * 4;
    const int c0 = (t & 15) * 4;
    float acc[4][4];
#pragma unroll
    for (int i = 0; i < 4; i++)
#pragma unroll
        for (int j = 0; j < 4; j++) acc[i][j] = bias[c0 + j];
#pragma unroll 4
    for (int kk = 0; kk < 128; ++kk) {
        float a0 = At[kk * 65 + r0 + 0];
        float a1 = At[kk * 65 + r0 + 1];
        float a2 = At[kk * 65 + r0 + 2];
        float a3 = At[kk * 65 + r0 + 3];
        const float4 w0 = *(const float4*)&Wt[kk * 64 + c0];
        float wj[4] = {w0.x, w0.y, w0.z, w0.w};
#pragma unroll
        for (int j = 0; j < 4; j++) {
            acc[0][j] += a0 * wj[j];
            acc[1][j] += a1 * wj[j];
            acc[2][j] += a2 * wj[j];
            acc[3][j] += a3 * wj[j];
        }
    }
#pragma unroll
    for (int i = 0; i < 4; i++)
#pragma unroll
        for (int j = 0; j < 4; j++)
            res_out[(size_t)(base + r0 + i) * 64 + c0 + j] =
                acc[i][j] + feats[(size_t)(base + r0 + i) * 64 + c0 + j];
}

extern "C" void kernel_launch(void* const* d_in, const int* in_sizes, int n_in,
                              void* d_out, int out_size, void* d_ws, size_t ws_size,
                              hipStream_t stream) {
    (void)in_sizes; (void)n_in; (void)out_size; (void)ws_size;
    const float* xyz   = (const float*)d_in[0];
    const float* feats = (const float*)d_in[2];
    const float* fc1_w = (const float*)d_in[3];
    const float* fc1_b = (const float*)d_in[4];
    const float* fc2_w = (const float*)d_in[5];
    const float* fc2_b = (const float*)d_in[6];
    const float* g1    = (const float*)d_in[7];
    const float* bg1   = (const float*)d_in[8];
    const float* g2    = (const float*)d_in[9];
    const float* bg2   = (const float*)d_in[10];
    const float* d1    = (const float*)d_in[11];
    const float* bd1   = (const float*)d_in[12];
    const float* d2    = (const float*)d_in[13];
    const float* bd2   = (const float*)d_in[14];
    const float* wq    = (const float*)d_in[15];
    const float* wk    = (const float*)d_in[16];
    const float* wv    = (const float*)d_in[17];

    int* idxw   = (int*)d_ws;
    float* xbuf = (float*)((char*)d_ws + (1 << 20));
    float* qbuf = xbuf + 2097152;
    float* kbuf = qbuf + 2097152;
    float* vbuf = kbuf + 2097152;
    float* rpre = vbuf + 2097152;
    __bf16* d2t = (__bf16*)(rpre + 2097152);
    __bf16* g1t = d2t + 16384;
    __bf16* g2t = g1t + 16384;

    float* res_out = (float*)d_out;
    float* attn    = res_out + 1048576;

    wprep_kernel<<<3, 256, 0, stream>>>(d2, g1, g2, d2t, g1t, g2t);
    knn_kernel<<<4096, 256, 0, stream>>>(xyz, idxw);
    gemm_x_kernel<<<256, 256, 0, stream>>>(feats, fc1_w, fc1_b, xbuf);
    gemm_qkv_kernel<<<dim3(256, 3), 256, 0, stream>>>(xbuf, wq, wk, wv, qbuf, kbuf, vbuf);
    k34_kernel<<<2048, 256, 0, stream>>>(xyz, idxw, qbuf, kbuf, d1, bd1, bd2, bg1, bg2,
                                         d2t, g1t, g2t, attn);
    k5_kernel<<<2048, 256, 0, stream>>>(xyz, idxw, vbuf, d1, bd1, bd2, d2t, attn, rpre);
    k6_kernel<<<256, 256, 0, stream>>>(rpre, fc2_w, fc2_b, feats, res_out);
}